// Round 6
// baseline (935.069 us; speedup 1.0000x reference)
//
#include <hip/hip_runtime.h>
#include <math.h>

#define N0   4096
#define D    512
#define NUM  8192
#define NCLS 100
#define KMIX 11

// ---- workspace layout (float offsets), fast path ----
#define OFF_NALL   0            // [NUM]
#define OFF_YALL   8192         // [NUM]
#define OFF_RLOSS  16384        // [NUM]
#define OFF_KSQ    24576        // [NUM]
#define OFF_MUSUM  32768        // slow: [NCLS*D] f32 | fast: muH [128][512] f16
#define OFF_CNT    83968        // [128]
#define OFF_KNN    84096        // [1] slow-path scalar
#define ZERO_N     51344        // MUSUM..KNN inclusive (slow path)
#define OFF_NMU    84112        // slow nmu [NCLS]
#define OFF_MUT    84224        // slow: [D][NCLS] f32 | fast: nmu_pad [128]
#define OFF_TK1S   135424       // fast: [4096][2*16]
#define OFF_TK1I   266496       // fast: [4096][2*16] int
#define OFF_TK2S   397568       // fast: [8192][8*8]
#define OFF_TK2I   921856       // fast: [8192][8*8] int
#define OFF_XH     1446144      // [NUM][512] f16 (2,097,152 floats)
// fast total = 3,543,296 floats = 14.2 MB
// slow-path top-k regions (R2 layout, non-overlapping):
#define SOFF_TK1S  135424       // [4096][44]
#define SOFF_TK1I  315648
#define SOFF_TK2S  495872       // [8192][8]
#define SOFF_TK2I  561408
#define NEED_BYTES ((size_t)15221760)   // unchanged: known-good threshold (R3-R5)

typedef _Float16 half8 __attribute__((ext_vector_type(8)));
typedef _Float16 half4v __attribute__((ext_vector_type(4)));
typedef float f32x4 __attribute__((ext_vector_type(4)));
typedef unsigned long long u64;

// Logical row r of the virtual [NUM][D] matrix (bitwise-identical everywhere)
__device__ __forceinline__ float4 ld_row4(const float* __restrict__ x, const int* __restrict__ perm,
                                          float lam, float om, int r, int col) {
  if (r < N0) {
    return *(const float4*)(x + (size_t)r * D + col);
  } else {
    int rr = r - N0;
    int p = perm[rr];
    float4 a = *(const float4*)(x + (size_t)rr * D + col);
    float4 b = *(const float4*)(x + (size_t)p * D + col);
    float4 m;
    m.x = lam * a.x + om * b.x;  m.y = lam * a.y + om * b.y;
    m.z = lam * a.z + om * b.z;  m.w = lam * a.w + om * b.w;
    return m;
  }
}

__device__ __forceinline__ void gld_lds16(const _Float16* g, _Float16* l) {
  __builtin_amdgcn_global_load_lds(
      (const __attribute__((address_space(1))) void*)g,
      (__attribute__((address_space(3))) void*)l, 16, 0, 0);
}

__device__ __forceinline__ unsigned sortable(float s) {
  unsigned u = __float_as_uint(s);
  return ((int)u < 0) ? ~u : (u | 0x80000000u);
}
__device__ __forceinline__ float unsortable(unsigned u) {
  return __uint_as_float(((int)u < 0) ? (u & 0x7fffffffu) : ~u);
}

__global__ __launch_bounds__(256) void k_zero(float* __restrict__ p, int n) {
  int i = blockIdx.x * 256 + threadIdx.x;
  if (i < n) p[i] = 0.f;
}

__global__ __launch_bounds__(256) void k_y(const float* __restrict__ y, float* __restrict__ y_all) {
  int i = blockIdx.x * 256 + threadIdx.x;
  if (i < N0) y_all[i] = y[i];
}

// fused: y_all init + exact fp32 norms + f16 conversion (x loaded once)
__global__ __launch_bounds__(64) void k_prep(const float* __restrict__ x, const float* __restrict__ y,
                                             const int* __restrict__ perm, const float* __restrict__ lam_p,
                                             _Float16* __restrict__ Xh, float* __restrict__ n_all,
                                             float* __restrict__ y_all) {
  int i = blockIdx.x;
  float lam = lam_p[0], om = 1.0f - lam;
  int t = threadIdx.x;
  float4 a = ld_row4(x, perm, lam, om, i, t * 4);
  float4 b = ld_row4(x, perm, lam, om, i, t * 4 + 256);
  half4v ha, hb;
  ha.x = (_Float16)a.x; ha.y = (_Float16)a.y; ha.z = (_Float16)a.z; ha.w = (_Float16)a.w;
  hb.x = (_Float16)b.x; hb.y = (_Float16)b.y; hb.z = (_Float16)b.z; hb.w = (_Float16)b.w;
  *(half4v*)(Xh + (size_t)i * D + t * 4) = ha;
  *(half4v*)(Xh + (size_t)i * D + t * 4 + 256) = hb;
  float s = a.x*a.x + a.y*a.y + a.z*a.z + a.w*a.w
          + b.x*b.x + b.y*b.y + b.z*b.z + b.w*b.w;
  #pragma unroll
  for (int o = 32; o > 0; o >>= 1) s += __shfl_down(s, o, 64);
  if (t == 0) {
    n_all[i] = s;
    if (i < N0) y_all[i] = y[i];
  }
}

// ---- MFMA kNN body v3: 128q x 128c tile, BK=64, dbuf, f16 score tile ----
// score = ||c||^2 - 2*dot_f16 (f16-quantized; exact fp32 re-rank downstream).
// LDS 65536 B: staging 2 x 32768 B; f16 scores [128 cand][132] (33792 B) and
// merge lists [2][128][M] u64 aliased inside.
template<int M, int NSPL>
__device__ __forceinline__ void knn_body128(
    const _Float16* __restrict__ Xq, const _Float16* __restrict__ Xc,
    const float* __restrict__ nC, int cb0, int nctiles, int row0, int split,
    float* __restrict__ outS, int* __restrict__ outI, char* smem)
{
  _Float16* St = (_Float16*)smem;      // staging, 2 bufs of 16384 halfs
  _Float16* Sh = (_Float16*)smem;      // f16 scores [cand][132] (aliased)
  u64* Lb = (u64*)smem;                // [2][128][M] (aliased)

  int tid = threadIdx.x;
  int wave = tid >> 6, lane = tid & 63;
  int wq = wave >> 1, wc = wave & 1;           // wave tile: 64q x 64c
  int col16 = lane & 15, quad = lane >> 4;

  // staging: wave stages Q segs {2w,2w+1}, C segs {2w,2w+1}; 2 k-chunks each
  const _Float16* qA = Xq + (size_t)((2 * wave) * 16 + col16) * D + quad * 8;
  const _Float16* qB = qA + (size_t)16 * D;
  int lQA = (2 * wave) * 1024 + lane * 8;
  int lQB = lQA + 1024;
  int lCA = 8192 + (2 * wave) * 1024 + lane * 8;
  int lCB = lCA + 1024;

  u64 keys[M];
  #pragma unroll
  for (int q = 0; q < M; q++) keys[q] = ~0ULL;

  int r_scan = tid >> 1, h_scan = tid & 1;     // 2 scan threads per query row

  for (int ct = 0; ct < nctiles; ct++) {
    int c0 = cb0 + ct * 128;
    const _Float16* cA = Xc + (size_t)(c0 + (2 * wave) * 16 + col16) * D + quad * 8;
    const _Float16* cB = cA + (size_t)16 * D;

    f32x4 acc[4][4];
    #pragma unroll
    for (int i = 0; i < 4; i++)
      #pragma unroll
      for (int j = 0; j < 4; j++) acc[i][j] = (f32x4){0.f, 0.f, 0.f, 0.f};

    // prologue: kk=0 into buf0 (prev c-tile's scan ended with a barrier)
    gld_lds16(qA,      St + lQA); gld_lds16(qA + 32, St + lQA + 512);
    gld_lds16(qB,      St + lQB); gld_lds16(qB + 32, St + lQB + 512);
    gld_lds16(cA,      St + lCA); gld_lds16(cA + 32, St + lCA + 512);
    gld_lds16(cB,      St + lCB); gld_lds16(cB + 32, St + lCB + 512);
    __syncthreads();

    #pragma unroll
    for (int t = 0; t < 8; t++) {
      const int cur = t & 1;
      if (t < 7) {
        int kk = (t + 1) * 64;
        _Float16* B = St + (cur ^ 1) * 16384;
        gld_lds16(qA + kk,      B + lQA); gld_lds16(qA + kk + 32, B + lQA + 512);
        gld_lds16(qB + kk,      B + lQB); gld_lds16(qB + kk + 32, B + lQB + 512);
        gld_lds16(cA + kk,      B + lCA); gld_lds16(cA + kk + 32, B + lCA + 512);
        gld_lds16(cB + kk,      B + lCB); gld_lds16(cB + kk + 32, B + lCB + 512);
      }
      const _Float16* Bc = St + cur * 16384;
      half8 a[4][2], b[4][2];
      #pragma unroll
      for (int i = 0; i < 4; i++)
        #pragma unroll
        for (int h = 0; h < 2; h++)
          a[i][h] = *(const half8*)(Bc + (wq * 4 + i) * 1024 + h * 512 + lane * 8);
      #pragma unroll
      for (int j = 0; j < 4; j++)
        #pragma unroll
        for (int h = 0; h < 2; h++)
          b[j][h] = *(const half8*)(Bc + 8192 + (wc * 4 + j) * 1024 + h * 512 + lane * 8);
      #pragma unroll
      for (int h = 0; h < 2; h++)
        #pragma unroll
        for (int i = 0; i < 4; i++)
          #pragma unroll
          for (int j = 0; j < 4; j++)
            acc[i][j] = __builtin_amdgcn_mfma_f32_16x16x32_f16(a[i][h], b[j][h], acc[i][j], 0, 0, 0);
      __syncthreads();
    }

    // epilogue: f16 transposed score store (C/D: col(c)=lane&15, row(q)=quad*4+reg)
    #pragma unroll
    for (int j = 0; j < 4; j++) {
      int cl = wc * 64 + j * 16 + col16;
      float ncv = nC[c0 + cl];
      #pragma unroll
      for (int i = 0; i < 4; i++) {
        half4v st;
        st.x = (_Float16)(ncv - 2.f * acc[i][j][0]);
        st.y = (_Float16)(ncv - 2.f * acc[i][j][1]);
        st.z = (_Float16)(ncv - 2.f * acc[i][j][2]);
        st.w = (_Float16)(ncv - 2.f * acc[i][j][3]);
        *(half4v*)&Sh[(size_t)cl * 132 + wq * 64 + i * 16 + quad * 4] = st;
      }
    }
    __syncthreads();

    // scan: 2 threads/row, 64 cands each; u16 reads, 2 lanes/bank (free)
    for (int c = h_scan * 64; c < h_scan * 64 + 64; c++) {
      float s = (float)Sh[c * 132 + r_scan];
      u64 key = ((u64)sortable(s) << 32) | (unsigned)(c0 + c);
      if (key < keys[M - 1]) {
        keys[M - 1] = key;
        #pragma unroll
        for (int p = M - 1; p > 0; p--) {
          if (keys[p] < keys[p - 1]) { u64 tmp = keys[p]; keys[p] = keys[p - 1]; keys[p - 1] = tmp; }
        }
      }
    }
    __syncthreads();   // scan done before next prologue overwrites smem
  }

  // merge 2 partial lists per row -> sorted top-M for this split
  #pragma unroll
  for (int q = 0; q < M; q++)
    Lb[((size_t)h_scan * 128 + r_scan) * M + q] = keys[q];
  __syncthreads();
  if (tid < 128) {
    const u64* L0 = Lb + (size_t)tid * M;
    const u64* L1 = Lb + (size_t)(128 + tid) * M;
    int p0 = 0, p1 = 0;
    size_t off = (size_t)(row0 + tid) * ((size_t)NSPL * M) + (size_t)split * M;
    #pragma unroll
    for (int q = 0; q < M; q++) {
      u64 k0 = (p0 < M) ? L0[p0] : ~0ULL;
      u64 k1 = (p1 < M) ? L1[p1] : ~0ULL;
      u64 b = k0 < k1 ? k0 : k1;
      if (b == k0) p0++; else p1++;
      outS[off + q] = unsortable((unsigned)(b >> 32));
      outI[off + q] = (int)(unsigned)b;
    }
  }
}

// 576 equal-ish blocks: [0,64) mixup (16 c-tiles, M=16, 2 splits) — long, first;
// [64,576) knn-reg (8 c-tiles, M=8, 8 splits). 2 blocks/CU -> near-perfect backfill.
__global__ __launch_bounds__(256, 2) void k_knn_all(const _Float16* __restrict__ Xh,
                                                    const float* __restrict__ n_all,
                                                    float* __restrict__ tk1s, int* __restrict__ tk1i,
                                                    float* __restrict__ tk2s, int* __restrict__ tk2i) {
  __shared__ __align__(16) char smem[65536];
  int bx = blockIdx.x;
  if (bx < 64) {             // mixup: 4096 mixed q vs 4096 x c
    int qblk = bx & 31, split = bx >> 5;
    knn_body128<16, 2>(Xh + (size_t)(N0 + qblk * 128) * D, Xh, n_all,
                       split * 2048, 16, qblk * 128, split, tk1s, tk1i, smem);
  } else {                   // knn reg: 8192 q vs 8192 c
    int b = bx - 64;
    int qblk = b & 63, split = b >> 6;
    knn_body128<8, 8>(Xh + (size_t)(qblk * 128) * D, Xh, n_all,
                      split * 1024, 8, qblk * 128, split, tk2s, tk2i, smem);
  }
}

// exact fp32 re-rank mixup: rank-select top-16 of 32 -> exact dists -> mode(11)
__global__ __launch_bounds__(256) void k_rr1(const float* __restrict__ x, const int* __restrict__ perm,
                                             const float* __restrict__ lam_p,
                                             const float* __restrict__ tks, const int* __restrict__ tki,
                                             const float* __restrict__ n_all, const float* __restrict__ y,
                                             float* __restrict__ y_all) {
  __shared__ u64 kl[32];
  __shared__ int sidx[16];
  __shared__ float sdot[16];
  int i = blockIdx.x;
  int t = threadIdx.x;
  float lam = lam_p[0], om = 1.f - lam;
  if (t < 32) {
    float s = tks[(size_t)i * 32 + t];
    int id = tki[(size_t)i * 32 + t];
    kl[t] = ((u64)sortable(s) << 32) | (unsigned)id;
  }
  __syncthreads();
  if (t < 32) {
    u64 me = kl[t];
    int rank = 0;
    #pragma unroll
    for (int j = 0; j < 32; j++) rank += (kl[j] < me) ? 1 : 0;
    if (rank < 16) sidx[rank] = (int)(unsigned)me;
  }
  __syncthreads();
  int g = t >> 4, l16 = t & 15;
  int c = sidx[g];
  float dot = 0.f;
  for (int d0 = l16 * 4; d0 < D; d0 += 64) {
    float4 q4 = ld_row4(x, perm, lam, om, N0 + i, d0);
    float4 c4 = *(const float4*)(x + (size_t)c * D + d0);
    dot += q4.x*c4.x + q4.y*c4.y + q4.z*c4.z + q4.w*c4.w;
  }
  #pragma unroll
  for (int o = 8; o > 0; o >>= 1) dot += __shfl_down(dot, o, 16);
  if (l16 == 0) sdot[g] = n_all[c] - 2.f * dot;
  __syncthreads();
  if (t == 0) {
    float es[16]; int ei[16];
    for (int q = 0; q < 16; q++) { es[q] = sdot[q]; ei[q] = sidx[q]; }
    for (int a = 1; a < 16; a++) {
      float s = es[a]; int id = ei[a];
      int b = a - 1;
      while (b >= 0 && (es[b] > s || (es[b] == s && ei[b] > id))) {
        es[b + 1] = es[b]; ei[b + 1] = ei[b]; b--;
      }
      es[b + 1] = s; ei[b + 1] = id;
    }
    float lab[KMIX];
    for (int q = 0; q < KMIX; q++) lab[q] = y[ei[q]];
    float best = 3.0e38f; int bestc = 0;
    for (int q = 0; q < KMIX; q++) {
      int cnt = 0;
      for (int r = 0; r < KMIX; r++) cnt += (lab[r] == lab[q]) ? 1 : 0;
      if (cnt > bestc || (cnt == bestc && lab[q] < best)) { bestc = cnt; best = lab[q]; }
    }
    y_all[N0 + i] = best;
  }
}

// exact fp32 re-rank knn reg: rank-select top-8 of 64 -> exact -> drop self, mode(3)
__global__ __launch_bounds__(256) void k_rr2(const float* __restrict__ x, const int* __restrict__ perm,
                                             const float* __restrict__ lam_p,
                                             const float* __restrict__ tks, const int* __restrict__ tki,
                                             const float* __restrict__ n_all, const float* __restrict__ y_all,
                                             float* __restrict__ ksq) {
  __shared__ u64 kl[64];
  __shared__ int sidx[8];
  __shared__ float sdot[8];
  int i = blockIdx.x;
  int t = threadIdx.x;
  float lam = lam_p[0], om = 1.f - lam;
  if (t < 64) {
    float s = tks[(size_t)i * 64 + t];
    int id = tki[(size_t)i * 64 + t];
    kl[t] = ((u64)sortable(s) << 32) | (unsigned)id;
  }
  __syncthreads();
  if (t < 64) {
    u64 me = kl[t];
    int rank = 0;
    #pragma unroll
    for (int j = 0; j < 64; j++) rank += (kl[j] < me) ? 1 : 0;
    if (rank < 8) sidx[rank] = (int)(unsigned)me;
  }
  __syncthreads();
  int g = t >> 5, l32 = t & 31;
  int c = sidx[g];
  float dot = 0.f;
  for (int d0 = l32 * 4; d0 < D; d0 += 128) {
    float4 q4 = ld_row4(x, perm, lam, om, i, d0);
    float4 c4 = ld_row4(x, perm, lam, om, c, d0);
    dot += q4.x*c4.x + q4.y*c4.y + q4.z*c4.z + q4.w*c4.w;
  }
  #pragma unroll
  for (int o = 16; o > 0; o >>= 1) dot += __shfl_down(dot, o, 32);
  if (l32 == 0) sdot[g] = n_all[c] - 2.f * dot;
  __syncthreads();
  if (t == 0) {
    float es[8]; int ei[8];
    for (int q = 0; q < 8; q++) { es[q] = sdot[q]; ei[q] = sidx[q]; }
    for (int a = 1; a < 8; a++) {
      float s = es[a]; int id = ei[a];
      int b = a - 1;
      while (b >= 0 && (es[b] > s || (es[b] == s && ei[b] > id))) {
        es[b + 1] = es[b]; ei[b + 1] = ei[b]; b--;
      }
      es[b + 1] = s; ei[b + 1] = id;
    }
    float l1 = y_all[ei[1]], l2 = y_all[ei[2]], l3 = y_all[ei[3]];
    int c1 = 1 + (int)(l2 == l1) + (int)(l3 == l1);
    int c2 = 1 + (int)(l1 == l2) + (int)(l3 == l2);
    int c3 = 1 + (int)(l1 == l3) + (int)(l2 == l3);
    int mc = c1 > c2 ? c1 : c2; mc = mc > c3 ? mc : c3;
    float mv = 3.0e38f;
    if (c1 == mc) mv = fminf(mv, l1);
    if (c2 == mc) mv = fminf(mv, l2);
    if (c3 == mc) mv = fminf(mv, l3);
    float d = mv - y_all[i];
    ksq[i] = d * d;
  }
}

// per-class mean via LDS row-list; writes f16 muH [128][512], nmu_pad, counts.
// f16 rounding of mu is exact-output-invariant (pi underflows to 0 regardless).
__global__ __launch_bounds__(256) void k_stats2h(const float* __restrict__ x, const int* __restrict__ perm,
                                                 const float* __restrict__ lam_p, const float* __restrict__ y_all,
                                                 _Float16* __restrict__ muH, float* __restrict__ nmu_pad,
                                                 float* __restrict__ counts) {
  __shared__ int cnt;
  __shared__ int lst[NUM];
  __shared__ int lstp[NUM];
  __shared__ float red[256];
  int c = blockIdx.x;
  int t = threadIdx.x;
  if (c >= NCLS) {
    for (int d = t; d < D; d += 256) muH[(size_t)c * D + d] = (_Float16)0.f;
    if (t == 0) { nmu_pad[c] = 0.f; counts[c] = 0.f; }
    return;
  }
  float lam = lam_p[0], om = 1.f - lam;
  float fc = (float)c;
  if (t == 0) cnt = 0;
  __syncthreads();
  for (int i = t; i < NUM; i += 256) {
    if (y_all[i] == fc) {
      int pos = atomicAdd(&cnt, 1);
      lst[pos] = i;
      lstp[pos] = (i >= N0) ? perm[i - N0] : 0;
    }
  }
  __syncthreads();
  int n = cnt;
  float a0 = 0.f, a1 = 0.f;
  for (int m = 0; m < n; m++) {
    int i = lst[m];
    if (i < N0) {
      a0 += x[(size_t)i * D + t];
      a1 += x[(size_t)i * D + t + 256];
    } else {
      int rr = i - N0, p = lstp[m];
      a0 += lam * x[(size_t)rr * D + t] + om * x[(size_t)p * D + t];
      a1 += lam * x[(size_t)rr * D + t + 256] + om * x[(size_t)p * D + t + 256];
    }
  }
  float inv = 1.f / fmaxf((float)n, 1.f);
  float v0 = a0 * inv, v1 = a1 * inv;
  muH[(size_t)c * D + t] = (_Float16)v0;
  muH[(size_t)c * D + t + 256] = (_Float16)v1;
  red[t] = v0 * v0 + v1 * v1;
  __syncthreads();
  for (int o = 128; o > 0; o >>= 1) { if (t < o) red[t] += red[t + o]; __syncthreads(); }
  if (t == 0) { nmu_pad[c] = red[0]; counts[c] = (float)n; }
}

// GM loss via MFMA GEMM (64 rows x 128 padded classes per block), R5-verified
__global__ __launch_bounds__(256) void k_gm2(const _Float16* __restrict__ Xh,
                                             const _Float16* __restrict__ muH,
                                             const float* __restrict__ nmu_pad,
                                             const float* __restrict__ counts,
                                             const float* __restrict__ n_all,
                                             const float* __restrict__ y_all,
                                             float* __restrict__ rloss) {
  __shared__ __align__(16) char smem[49152];
  float* Ss = (float*)smem;
  _Float16* St = (_Float16*)smem;

  int tid = threadIdx.x;
  int wave = tid >> 6, lane = tid & 63;
  int wq = wave >> 1, wc = wave & 1;
  int col16 = lane & 15, quad = lane >> 4;
  int qb = blockIdx.x * 64;

  const _Float16* qg = Xh + (size_t)(qb + wave * 16 + col16) * D + quad * 8;
  int csegA = 2 * wave, csegB = 2 * wave + 1;
  const _Float16* cgA = muH + (size_t)(csegA * 16 + col16) * D + quad * 8;
  const _Float16* cgB = cgA + (size_t)16 * D;
  int ldsQ = wave * 1024 + lane * 8;
  int ldsCA = 4096 + csegA * 1024 + lane * 8;
  int ldsCB = 4096 + csegB * 1024 + lane * 8;

  f32x4 acc[2][4];
  #pragma unroll
  for (int i = 0; i < 2; i++)
    #pragma unroll
    for (int j = 0; j < 4; j++) acc[i][j] = (f32x4){0.f, 0.f, 0.f, 0.f};

  gld_lds16(qg,       St + ldsQ);
  gld_lds16(qg + 32,  St + ldsQ + 512);
  gld_lds16(cgA,      St + ldsCA);
  gld_lds16(cgA + 32, St + ldsCA + 512);
  gld_lds16(cgB,      St + ldsCB);
  gld_lds16(cgB + 32, St + ldsCB + 512);
  __syncthreads();

  #pragma unroll
  for (int t = 0; t < 8; t++) {
    const int cur = t & 1;
    if (t < 7) {
      int kk = (t + 1) * 64;
      _Float16* B = St + (cur ^ 1) * 12288;
      gld_lds16(qg + kk,       B + ldsQ);
      gld_lds16(qg + kk + 32,  B + ldsQ + 512);
      gld_lds16(cgA + kk,      B + ldsCA);
      gld_lds16(cgA + kk + 32, B + ldsCA + 512);
      gld_lds16(cgB + kk,      B + ldsCB);
      gld_lds16(cgB + kk + 32, B + ldsCB + 512);
    }
    const _Float16* Bc = St + cur * 12288;
    half8 a[2][2], b[4][2];
    #pragma unroll
    for (int i = 0; i < 2; i++)
      #pragma unroll
      for (int h = 0; h < 2; h++)
        a[i][h] = *(const half8*)(Bc + (wq * 2 + i) * 1024 + h * 512 + lane * 8);
    #pragma unroll
    for (int j = 0; j < 4; j++)
      #pragma unroll
      for (int h = 0; h < 2; h++)
        b[j][h] = *(const half8*)(Bc + 4096 + (wc * 4 + j) * 1024 + h * 512 + lane * 8);
    #pragma unroll
    for (int h = 0; h < 2; h++)
      #pragma unroll
      for (int i = 0; i < 2; i++)
        #pragma unroll
        for (int j = 0; j < 4; j++)
          acc[i][j] = __builtin_amdgcn_mfma_f32_16x16x32_f16(a[i][h], b[j][h], acc[i][j], 0, 0, 0);
    __syncthreads();
  }

  #pragma unroll
  for (int j = 0; j < 4; j++) {
    int c_local = wc * 64 + j * 16 + col16;
    float ncv = nmu_pad[c_local];
    #pragma unroll
    for (int i = 0; i < 2; i++) {
      float4 st;
      st.x = ncv - 2.f * acc[i][j][0];
      st.y = ncv - 2.f * acc[i][j][1];
      st.z = ncv - 2.f * acc[i][j][2];
      st.w = ncv - 2.f * acc[i][j][3];
      *(float4*)&Ss[(size_t)c_local * 68 + wq * 32 + i * 16 + quad * 4] = st;
    }
  }
  __syncthreads();

  int r = tid & 63, h = tid >> 6;
  float* redm = (float*)(smem + 35840);
  float* mrow = (float*)(smem + 36864);
  float* Sp   = (float*)(smem + 37120);
  float* Ep   = (float*)(smem + 38144);
  float* Yp   = (float*)(smem + 39168);

  float mymin = 3.0e38f;
  for (int c = h * 32; c < h * 32 + 32; c++) {
    if (c < NCLS && counts[c] > 0.f) mymin = fminf(mymin, Ss[c * 68 + r]);
  }
  redm[h * 64 + r] = mymin;
  __syncthreads();
  if (tid < 64) {
    float ms = fminf(fminf(redm[tid], redm[64 + tid]), fminf(redm[128 + tid], redm[192 + tid]));
    mrow[tid] = ms;
  }
  __syncthreads();
  float ms = mrow[r];
  int yc = (int)y_all[qb + r];
  float Sv = 0.f, Se2 = 0.f, ey = 0.f;
  for (int c = h * 32; c < h * 32 + 32; c++) {
    if (c < NCLS && counts[c] > 0.f) {
      float e = expf(-0.5f * (Ss[c * 68 + r] - ms));
      Sv += e; Se2 += e * e;
      if (c == yc) ey = e;
    }
  }
  Sp[h * 64 + r] = Sv; Ep[h * 64 + r] = Se2; Yp[h * 64 + r] = ey;
  __syncthreads();
  if (tid < 64) {
    float S4 = Sp[tid] + Sp[64 + tid] + Sp[128 + tid] + Sp[192 + tid];
    float E4 = Ep[tid] + Ep[64 + tid] + Ep[128 + tid] + Ep[192 + tid];
    float Y4 = Yp[tid] + Yp[64 + tid] + Yp[128 + tid] + Yp[192 + tid];
    float m = n_all[qb + tid] + mrow[tid];
    float E = expf(-0.5f * m);          // underflows to 0 -> pi == 0 -> loss 1
    float denom = E * S4 + 1e-15f;
    float f = E / denom;
    rloss[qb + tid] = E4 * f * f - 2.f * Y4 * f + 1.f;
  }
}

__global__ __launch_bounds__(256) void k_final_fast(const float* __restrict__ row_loss,
                                                    const float* __restrict__ ksq, float* __restrict__ out) {
  __shared__ float red[256];
  int t = threadIdx.x;
  float s = 0.f;
  for (int i = t; i < NUM; i += 256) s += row_loss[i] + 0.01f * ksq[i];
  red[t] = s;
  __syncthreads();
  for (int o = 128; o > 0; o >>= 1) { if (t < o) red[t] += red[t + o]; __syncthreads(); }
  if (t == 0) out[0] = red[0] / (float)NUM;
}

// ================= fp32 fallback path (R2, passed absmax 0.0) =================
#define QT 32
#define CTF 128
#define BKF 32

__global__ __launch_bounds__(64) void k_norms(const float* __restrict__ x, const int* __restrict__ perm,
                                              const float* __restrict__ lam_p, float* __restrict__ n_all) {
  int i = blockIdx.x;
  float lam = lam_p[0], om = 1.0f - lam;
  int t = threadIdx.x;
  float4 a = ld_row4(x, perm, lam, om, i, t * 4);
  float4 b = ld_row4(x, perm, lam, om, i, t * 4 + 256);
  float s = a.x*a.x + a.y*a.y + a.z*a.z + a.w*a.w
          + b.x*b.x + b.y*b.y + b.z*b.z + b.w*b.w;
  #pragma unroll
  for (int o = 32; o > 0; o >>= 1) s += __shfl_down(s, o, 64);
  if (t == 0) n_all[i] = s;
}

template<int KK>
__global__ __launch_bounds__(256) void k_knn_f32(const float* __restrict__ x, const int* __restrict__ perm,
                                                 const float* __restrict__ lam_p, int qstart,
                                                 const float* __restrict__ nC, int candPerSplit, int nsplits,
                                                 float* __restrict__ outS, int* __restrict__ outI) {
  __shared__ float Qs[BKF][QT + 4];
  __shared__ float Cs[BKF][CTF + 4];
  __shared__ float Sf[QT][CTF + 4];

  int tid = threadIdx.x;
  float lam = lam_p[0], om = 1.0f - lam;
  int qbase = blockIdx.x * QT;
  int cb = blockIdx.y * candPerSplit;
  int ce = cb + candPerSplit;

  int cx = tid & 31;
  int ry = tid >> 5;
  int lr = tid >> 3;
  int kc = (tid & 7) * 4;

  float ks[KK]; int ki[KK];
  #pragma unroll
  for (int q = 0; q < KK; q++) { ks[q] = 3.0e38f; ki[q] = 0x7fffffff; }

  for (int c0 = cb; c0 < ce; c0 += CTF) {
    float acc[4][4];
    #pragma unroll
    for (int i = 0; i < 4; i++)
      #pragma unroll
      for (int j = 0; j < 4; j++) acc[i][j] = 0.f;

    for (int kk = 0; kk < D; kk += BKF) {
      __syncthreads();
      {
        float4 v = ld_row4(x, perm, lam, om, qstart + qbase + lr, kk + kc);
        Qs[kc + 0][lr] = v.x; Qs[kc + 1][lr] = v.y; Qs[kc + 2][lr] = v.z; Qs[kc + 3][lr] = v.w;
      }
      #pragma unroll
      for (int rr = 0; rr < 4; rr++) {
        int r = lr + rr * 32;
        float4 v = ld_row4(x, perm, lam, om, c0 + r, kk + kc);
        Cs[kc + 0][r] = v.x; Cs[kc + 1][r] = v.y; Cs[kc + 2][r] = v.z; Cs[kc + 3][r] = v.w;
      }
      __syncthreads();
      #pragma unroll
      for (int k = 0; k < BKF; k++) {
        float4 a4 = *(const float4*)&Qs[k][ry * 4];
        float4 b4 = *(const float4*)&Cs[k][cx * 4];
        float av[4] = {a4.x, a4.y, a4.z, a4.w};
        float bv[4] = {b4.x, b4.y, b4.z, b4.w};
        #pragma unroll
        for (int i = 0; i < 4; i++)
          #pragma unroll
          for (int j = 0; j < 4; j++) acc[i][j] += av[i] * bv[j];
      }
    }
    __syncthreads();
    {
      float4 nc4 = *(const float4*)&nC[c0 + cx * 4];
      float ncv[4] = {nc4.x, nc4.y, nc4.z, nc4.w};
      #pragma unroll
      for (int i = 0; i < 4; i++)
        #pragma unroll
        for (int j = 0; j < 4; j++)
          Sf[ry * 4 + i][cx * 4 + j] = ncv[j] - 2.0f * acc[i][j];
    }
    __syncthreads();
    if (tid < QT) {
      for (int c = 0; c < CTF; c++) {
        float s = Sf[tid][c];
        int j = c0 + c;
        bool worse = (s > ks[KK - 1]) || (s == ks[KK - 1] && j > ki[KK - 1]);
        if (!worse) {
          ks[KK - 1] = s; ki[KK - 1] = j;
          #pragma unroll
          for (int p = KK - 1; p > 0; p--) {
            bool sw = (ks[p] < ks[p - 1]) || (ks[p] == ks[p - 1] && ki[p] < ki[p - 1]);
            if (sw) {
              float ts = ks[p]; ks[p] = ks[p - 1]; ks[p - 1] = ts;
              int ti = ki[p]; ki[p] = ki[p - 1]; ki[p - 1] = ti;
            }
          }
        }
      }
    }
  }

  if (tid < QT) {
    int row = qbase + tid;
    size_t off = (size_t)row * (nsplits * KK) + (size_t)blockIdx.y * KK;
    #pragma unroll
    for (int q = 0; q < KK; q++) { outS[off + q] = ks[q]; outI[off + q] = ki[q]; }
  }
}

__global__ __launch_bounds__(256) void k_final1(const float* __restrict__ tks, const int* __restrict__ tki,
                                                const float* __restrict__ y, float* __restrict__ y_all) {
  int i = blockIdx.x * 256 + threadIdx.x;
  if (i >= N0) return;
  const float* sb = tks + (size_t)i * 44;
  const int* ib = tki + (size_t)i * 44;
  int p0 = 0, p1 = 0, p2 = 0, p3 = 0;
  float lab[KMIX];
  #pragma unroll
  for (int q = 0; q < KMIX; q++) {
    float bs = 3.0e38f; int bi = 0x7fffffff; int w = 0;
    if (p0 < 11) { float s = sb[p0];      int id = ib[p0];      if (s < bs || (s == bs && id < bi)) { bs = s; bi = id; w = 0; } }
    if (p1 < 11) { float s = sb[11 + p1]; int id = ib[11 + p1]; if (s < bs || (s == bs && id < bi)) { bs = s; bi = id; w = 1; } }
    if (p2 < 11) { float s = sb[22 + p2]; int id = ib[22 + p2]; if (s < bs || (s == bs && id < bi)) { bs = s; bi = id; w = 2; } }
    if (p3 < 11) { float s = sb[33 + p3]; int id = ib[33 + p3]; if (s < bs || (s == bs && id < bi)) { bs = s; bi = id; w = 3; } }
    if (w == 0) p0++; else if (w == 1) p1++; else if (w == 2) p2++; else p3++;
    lab[q] = y[bi];
  }
  float best = 3.0e38f; int bestc = 0;
  #pragma unroll
  for (int q = 0; q < KMIX; q++) {
    int c = 0;
    #pragma unroll
    for (int r = 0; r < KMIX; r++) c += (lab[r] == lab[q]) ? 1 : 0;
    if (c > bestc || (c == bestc && lab[q] < best)) { bestc = c; best = lab[q]; }
  }
  y_all[N0 + i] = best;
}

__global__ __launch_bounds__(128) void k_stats(const float* __restrict__ x, const int* __restrict__ perm,
                                               const float* __restrict__ lam_p, const float* __restrict__ y_all,
                                               float* __restrict__ mu_sum, float* __restrict__ counts) {
  int i = blockIdx.x;
  float lam = lam_p[0], om = 1.0f - lam;
  int c = (int)y_all[i];
  float* ms = mu_sum + (size_t)c * D;
  int t = threadIdx.x;
  float4 v = ld_row4(x, perm, lam, om, i, t * 4);
  atomicAdd(&ms[t * 4 + 0], v.x);
  atomicAdd(&ms[t * 4 + 1], v.y);
  atomicAdd(&ms[t * 4 + 2], v.z);
  atomicAdd(&ms[t * 4 + 3], v.w);
  if (t == 0) atomicAdd(&counts[c], 1.0f);
}

__global__ __launch_bounds__(256) void k_mufin(const float* __restrict__ mu_sum, const float* __restrict__ counts,
                                               float* __restrict__ muT, float* __restrict__ nmu) {
  __shared__ float red[256];
  int c = blockIdx.x;
  float inv = 1.0f / fmaxf(counts[c], 1.0f);
  int t = threadIdx.x;
  float v0 = mu_sum[(size_t)c * D + t] * inv;
  float v1 = mu_sum[(size_t)c * D + t + 256] * inv;
  muT[(size_t)t * NCLS + c] = v0;
  muT[(size_t)(t + 256) * NCLS + c] = v1;
  red[t] = v0 * v0 + v1 * v1;
  __syncthreads();
  for (int o = 128; o > 0; o >>= 1) { if (t < o) red[t] += red[t + o]; __syncthreads(); }
  if (t == 0) nmu[c] = red[0];
}

__global__ __launch_bounds__(256) void k_final2(const float* __restrict__ t2s, const int* __restrict__ t2i,
                                                const float* __restrict__ y_all, float* __restrict__ knn_acc) {
  __shared__ float red[256];
  int i = blockIdx.x * 256 + threadIdx.x;
  float dd2 = 0.f;
  if (i < NUM) {
    const float* sA = t2s + (size_t)i * 8; const float* sB = sA + 4;
    const int* iA = t2i + (size_t)i * 8;   const int* iB = iA + 4;
    int pa = 0, pb = 0;
    int midx[4];
    #pragma unroll
    for (int q = 0; q < 4; q++) {
      float sa = (pa < 4) ? sA[pa] : 3.0e38f;
      float sb = (pb < 4) ? sB[pb] : 3.0e38f;
      int ia = (pa < 4) ? iA[pa] : 0x7fffffff;
      int ib = (pb < 4) ? iB[pb] : 0x7fffffff;
      bool ta = (sa < sb) || (sa == sb && ia < ib);
      midx[q] = ta ? ia : ib;
      if (ta) pa++; else pb++;
    }
    float l1 = y_all[midx[1]], l2 = y_all[midx[2]], l3 = y_all[midx[3]];
    int c1 = 1 + (int)(l2 == l1) + (int)(l3 == l1);
    int c2 = 1 + (int)(l1 == l2) + (int)(l3 == l2);
    int c3 = 1 + (int)(l1 == l3) + (int)(l2 == l3);
    int mc = c1 > c2 ? c1 : c2; mc = mc > c3 ? mc : c3;
    float mv = 3.0e38f;
    if (c1 == mc) mv = fminf(mv, l1);
    if (c2 == mc) mv = fminf(mv, l2);
    if (c3 == mc) mv = fminf(mv, l3);
    float d = mv - y_all[i];
    dd2 = d * d;
  }
  red[threadIdx.x] = dd2;
  __syncthreads();
  for (int o = 128; o > 0; o >>= 1) { if (threadIdx.x < o) red[threadIdx.x] += red[threadIdx.x + o]; __syncthreads(); }
  if (threadIdx.x == 0) atomicAdd(knn_acc, red[0]);
}

__global__ __launch_bounds__(128) void k_gm(const float* __restrict__ x, const int* __restrict__ perm,
                                            const float* __restrict__ lam_p, const float* __restrict__ y_all,
                                            const float* __restrict__ n_all, const float* __restrict__ muT,
                                            const float* __restrict__ nmu, const float* __restrict__ counts,
                                            float* __restrict__ row_loss) {
  __shared__ float red[128];
  int i = blockIdx.x;
  int t = threadIdx.x;
  float lam = lam_p[0], om = 1.0f - lam;
  bool valid = (t < NCLS) && (counts[t] > 0.f);
  float d2 = 3.0e38f;
  if (t < NCLS) {
    float dot = 0.f;
    for (int d = 0; d < D; d += 4) {
      float4 v = ld_row4(x, perm, lam, om, i, d);
      dot += v.x * muT[(size_t)(d + 0) * NCLS + t];
      dot += v.y * muT[(size_t)(d + 1) * NCLS + t];
      dot += v.z * muT[(size_t)(d + 2) * NCLS + t];
      dot += v.w * muT[(size_t)(d + 3) * NCLS + t];
    }
    d2 = n_all[i] + nmu[t] - 2.f * dot;
  }
  red[t] = valid ? d2 : 3.0e38f;
  __syncthreads();
  for (int o = 64; o > 0; o >>= 1) { if (t < o) red[t] = fminf(red[t], red[t + o]); __syncthreads(); }
  float m = red[0];
  __syncthreads();
  float e = valid ? expf(-0.5f * (d2 - m)) : 0.f;
  red[t] = e;
  __syncthreads();
  for (int o = 64; o > 0; o >>= 1) { if (t < o) red[t] += red[t + o]; __syncthreads(); }
  float S = red[0];
  __syncthreads();
  float E = expf(-0.5f * m);
  float denom = E * S + 1e-15f;
  float pi = e * E / denom;
  pi = fminf(fmaxf(pi, 0.f), 1.f);
  int yc = (int)y_all[i];
  float term = pi * pi - 2.f * ((t == yc) ? pi : 0.f);
  red[t] = valid ? term : 0.f;
  __syncthreads();
  for (int o = 64; o > 0; o >>= 1) { if (t < o) red[t] += red[t + o]; __syncthreads(); }
  if (t == 0) row_loss[i] = red[0] + 1.0f;
}

__global__ __launch_bounds__(256) void k_final_slow(const float* __restrict__ row_loss,
                                                    const float* __restrict__ knn_acc, float* __restrict__ out) {
  __shared__ float red[256];
  int t = threadIdx.x;
  float s = 0.f;
  for (int i = t; i < NUM; i += 256) s += row_loss[i];
  red[t] = s;
  __syncthreads();
  for (int o = 128; o > 0; o >>= 1) { if (t < o) red[t] += red[t + o]; __syncthreads(); }
  if (t == 0) out[0] = red[0] / (float)NUM + 0.01f * (knn_acc[0] / (float)NUM);
}

extern "C" void kernel_launch(void* const* d_in, const int* in_sizes, int n_in,
                              void* d_out, int out_size, void* d_ws, size_t ws_size,
                              hipStream_t stream) {
  const float* x   = (const float*)d_in[0];
  const float* y   = (const float*)d_in[1];
  const float* lam = (const float*)d_in[2];
  const int* perm  = (const int*)d_in[3];
  float* ws = (float*)d_ws;

  float* n_all  = ws + OFF_NALL;
  float* y_all  = ws + OFF_YALL;
  float* rloss  = ws + OFF_RLOSS;
  float* ksq    = ws + OFF_KSQ;
  float* mu_sum = ws + OFF_MUSUM;
  float* counts = ws + OFF_CNT;
  float* knn_acc= ws + OFF_KNN;
  float* nmu    = ws + OFF_NMU;
  float* muT    = ws + OFF_MUT;
  _Float16* Xh  = (_Float16*)(ws + OFF_XH);
  _Float16* muH = (_Float16*)(ws + OFF_MUSUM);
  float* nmu_pad= ws + OFF_MUT;

  bool fast = ws_size >= NEED_BYTES;   // constant per-process: same path every call

  if (fast) {
    float* tk1s = ws + OFF_TK1S;  int* tk1i = (int*)(ws + OFF_TK1I);
    float* tk2s = ws + OFF_TK2S;  int* tk2i = (int*)(ws + OFF_TK2I);
    k_prep<<<NUM, 64, 0, stream>>>(x, y, perm, lam, Xh, n_all, y_all);
    k_knn_all<<<576, 256, 0, stream>>>(Xh, n_all, tk1s, tk1i, tk2s, tk2i);
    k_rr1<<<N0, 256, 0, stream>>>(x, perm, lam, tk1s, tk1i, n_all, y, y_all);
    k_stats2h<<<128, 256, 0, stream>>>(x, perm, lam, y_all, muH, nmu_pad, counts);
    k_rr2<<<NUM, 256, 0, stream>>>(x, perm, lam, tk2s, tk2i, n_all, y_all, ksq);
    k_gm2<<<NUM / 64, 256, 0, stream>>>(Xh, muH, nmu_pad, counts, n_all, y_all, rloss);
    k_final_fast<<<1, 256, 0, stream>>>(rloss, ksq, (float*)d_out);
  } else {
    float* tk1s = ws + SOFF_TK1S;  int* tk1i = (int*)(ws + SOFF_TK1I);
    float* tk2s = ws + SOFF_TK2S;  int* tk2i = (int*)(ws + SOFF_TK2I);
    k_y<<<(N0 + 255) / 256, 256, 0, stream>>>(y, y_all);
    k_zero<<<(ZERO_N + 255) / 256, 256, 0, stream>>>(mu_sum, ZERO_N);
    k_norms<<<NUM, 64, 0, stream>>>(x, perm, lam, n_all);
    dim3 g1(N0 / QT, 4);
    k_knn_f32<KMIX><<<g1, 256, 0, stream>>>(x, perm, lam, N0, n_all, N0 / 4, 4, tk1s, tk1i);
    k_final1<<<(N0 + 255) / 256, 256, 0, stream>>>(tk1s, tk1i, y, y_all);
    k_stats<<<NUM, 128, 0, stream>>>(x, perm, lam, y_all, mu_sum, counts);
    k_mufin<<<NCLS, 256, 0, stream>>>(mu_sum, counts, muT, nmu);
    dim3 g2(NUM / QT, 2);
    k_knn_f32<4><<<g2, 256, 0, stream>>>(x, perm, lam, 0, n_all, NUM / 2, 2, tk2s, tk2i);
    k_final2<<<NUM / 256, 256, 0, stream>>>(tk2s, tk2i, y_all, knn_acc);
    k_gm<<<NUM, 128, 0, stream>>>(x, perm, lam, y_all, n_all, muT, nmu, counts, rloss);
    k_final_slow<<<1, 256, 0, stream>>>(rloss, knn_acc, (float*)d_out);
  }
}

// Round 7
// 633.440 us; speedup vs baseline: 1.4762x; 1.4762x over previous
//
#include <hip/hip_runtime.h>
#include <math.h>

#define N0   4096
#define D    512
#define NUM  8192
#define NCLS 100
#define KMIX 11

// ---- workspace layout (float offsets) ---- (R5 layout, 15.2 MB)
#define OFF_NALL   0            // [NUM]
#define OFF_YALL   8192         // [NUM]
#define OFF_RLOSS  16384        // [NUM]
#define OFF_KSQ    24576        // [NUM]
#define OFF_MUSUM  32768        // slow: [NCLS*D] f32 | fast: muH [128][512] f16
#define OFF_CNT    83968        // [128]
#define OFF_KNN    84096        // [1] slow-path scalar
#define ZERO_N     51344        // MUSUM..KNN inclusive (slow path)
#define OFF_NMU    84112        // slow nmu [NCLS]
#define OFF_MUT    84224        // slow: [D][NCLS] f32 | fast: nmu_pad [128]
#define OFF_TK1S   135424       // fast: [4096][8*16] / slow: [4096][4*11]
#define OFF_TK1I   659712
#define OFF_TK2S   1184000      // fast: [8192][4*8] / slow: [8192][2*4]
#define OFF_TK2I   1446144
#define OFF_XH     1708288      // [NUM][512] f16
#define TOTAL_F    3805440
#define NEED_BYTES ((size_t)TOTAL_F * 4)   // 15,221,760

typedef _Float16 half8 __attribute__((ext_vector_type(8)));
typedef _Float16 half4v __attribute__((ext_vector_type(4)));
typedef float f32x4 __attribute__((ext_vector_type(4)));
typedef unsigned long long u64;

// Logical row r of the virtual [NUM][D] matrix (bitwise-identical everywhere)
__device__ __forceinline__ float4 ld_row4(const float* __restrict__ x, const int* __restrict__ perm,
                                          float lam, float om, int r, int col) {
  if (r < N0) {
    return *(const float4*)(x + (size_t)r * D + col);
  } else {
    int rr = r - N0;
    int p = perm[rr];
    float4 a = *(const float4*)(x + (size_t)rr * D + col);
    float4 b = *(const float4*)(x + (size_t)p * D + col);
    float4 m;
    m.x = lam * a.x + om * b.x;  m.y = lam * a.y + om * b.y;
    m.z = lam * a.z + om * b.z;  m.w = lam * a.w + om * b.w;
    return m;
  }
}

__device__ __forceinline__ void gld_lds16(const _Float16* g, _Float16* l) {
  __builtin_amdgcn_global_load_lds(
      (const __attribute__((address_space(1))) void*)g,
      (__attribute__((address_space(3))) void*)l, 16, 0, 0);
}

__device__ __forceinline__ unsigned sortable(float s) {
  unsigned u = __float_as_uint(s);
  return ((int)u < 0) ? ~u : (u | 0x80000000u);
}
__device__ __forceinline__ float unsortable(unsigned u) {
  return __uint_as_float(((int)u < 0) ? (u & 0x7fffffffu) : ~u);
}

__global__ __launch_bounds__(256) void k_zero(float* __restrict__ p, int n) {
  int i = blockIdx.x * 256 + threadIdx.x;
  if (i < n) p[i] = 0.f;
}

__global__ __launch_bounds__(256) void k_y(const float* __restrict__ y, float* __restrict__ y_all) {
  int i = blockIdx.x * 256 + threadIdx.x;
  if (i < N0) y_all[i] = y[i];
}

// fused: y_all init + exact fp32 norms + f16 conversion (x loaded once)
__global__ __launch_bounds__(64) void k_prep(const float* __restrict__ x, const float* __restrict__ y,
                                             const int* __restrict__ perm, const float* __restrict__ lam_p,
                                             _Float16* __restrict__ Xh, float* __restrict__ n_all,
                                             float* __restrict__ y_all) {
  int i = blockIdx.x;
  float lam = lam_p[0], om = 1.0f - lam;
  int t = threadIdx.x;
  float4 a = ld_row4(x, perm, lam, om, i, t * 4);
  float4 b = ld_row4(x, perm, lam, om, i, t * 4 + 256);
  half4v ha, hb;
  ha.x = (_Float16)a.x; ha.y = (_Float16)a.y; ha.z = (_Float16)a.z; ha.w = (_Float16)a.w;
  hb.x = (_Float16)b.x; hb.y = (_Float16)b.y; hb.z = (_Float16)b.z; hb.w = (_Float16)b.w;
  *(half4v*)(Xh + (size_t)i * D + t * 4) = ha;
  *(half4v*)(Xh + (size_t)i * D + t * 4 + 256) = hb;
  float s = a.x*a.x + a.y*a.y + a.z*a.z + a.w*a.w
          + b.x*b.x + b.y*b.y + b.z*b.z + b.w*b.w;
  #pragma unroll
  for (int o = 32; o > 0; o >>= 1) s += __shfl_down(s, o, 64);
  if (t == 0) {
    n_all[i] = s;
    if (i < N0) y_all[i] = y[i];
  }
}

// ---- MFMA kNN body v4: 64q x 128c, BK=64, dbuf, f16 scores in buf1 region,
// next-tile K0 prefetch at t=7 (removes per-tile prologue stall).
// LDS 49152 B: buf0 [0,24576), buf1 [24576,49152); f16 scores [128][68]
// at 24576 (inside buf1, 17408 B); merge lists aliased at base.
template<int M, int NSPL>
__device__ __forceinline__ void knn_body(const _Float16* __restrict__ Xq,
                                         const _Float16* __restrict__ Xc,
                                         const float* __restrict__ nC,
                                         int cb0, int nctiles, int row0, int split,
                                         float* __restrict__ outS, int* __restrict__ outI,
                                         char* smem) {
  _Float16* St = (_Float16*)smem;                  // staging bufs, 12288 halfs each
  _Float16* Sh = (_Float16*)(smem + 24576);        // f16 scores [cand][68]
  u64* Lb = (u64*)smem;                            // [4][64][M] merge lists

  int tid = threadIdx.x;
  int wave = tid >> 6, lane = tid & 63;
  int wq = wave >> 1, wc = wave & 1;               // wave tile: 32q x 64c
  int col16 = lane & 15, quad = lane >> 4;

  const _Float16* qg = Xq + (size_t)(wave * 16 + col16) * D + quad * 8;
  int csegA = 2 * wave, csegB = 2 * wave + 1;
  int ldsQ = wave * 1024 + lane * 8;
  int ldsCA = 4096 + csegA * 1024 + lane * 8;
  int ldsCB = 4096 + csegB * 1024 + lane * 8;

  u64 keys[M];
  #pragma unroll
  for (int q = 0; q < M; q++) keys[q] = ~0ULL;

  int r_scan = tid & 63, h_scan = tid >> 6;        // 4 scan threads per query row

  // prologue: tile 0, K0 -> buf0
  {
    const _Float16* cA = Xc + (size_t)(cb0 + csegA * 16 + col16) * D + quad * 8;
    const _Float16* cB = cA + (size_t)16 * D;
    gld_lds16(qg,      St + ldsQ);  gld_lds16(qg + 32, St + ldsQ + 512);
    gld_lds16(cA,      St + ldsCA); gld_lds16(cA + 32, St + ldsCA + 512);
    gld_lds16(cB,      St + ldsCB); gld_lds16(cB + 32, St + ldsCB + 512);
  }
  __syncthreads();

  for (int ct = 0; ct < nctiles; ct++) {
    int c0 = cb0 + ct * 128;
    const _Float16* cgA = Xc + (size_t)(c0 + csegA * 16 + col16) * D + quad * 8;
    const _Float16* cgB = cgA + (size_t)16 * D;

    f32x4 acc[2][4];
    #pragma unroll
    for (int i = 0; i < 2; i++)
      #pragma unroll
      for (int j = 0; j < 4; j++) acc[i][j] = (f32x4){0.f, 0.f, 0.f, 0.f};

    #pragma unroll
    for (int t = 0; t < 8; t++) {
      const int cur = t & 1;
      if (t < 7) {               // prefetch same-tile next K-chunk
        int kk = (t + 1) * 64;
        _Float16* B = St + (cur ^ 1) * 12288;
        gld_lds16(qg + kk,       B + ldsQ);  gld_lds16(qg + kk + 32,  B + ldsQ + 512);
        gld_lds16(cgA + kk,      B + ldsCA); gld_lds16(cgA + kk + 32, B + ldsCA + 512);
        gld_lds16(cgB + kk,      B + ldsCB); gld_lds16(cgB + kk + 32, B + ldsCB + 512);
      } else if (ct + 1 < nctiles) {   // prefetch NEXT tile's K0 -> buf0 (dead now)
        const _Float16* nA = cgA + (size_t)128 * D;
        const _Float16* nB = cgB + (size_t)128 * D;
        gld_lds16(qg,      St + ldsQ);  gld_lds16(qg + 32, St + ldsQ + 512);
        gld_lds16(nA,      St + ldsCA); gld_lds16(nA + 32, St + ldsCA + 512);
        gld_lds16(nB,      St + ldsCB); gld_lds16(nB + 32, St + ldsCB + 512);
      }
      const _Float16* Bc = St + cur * 12288;
      half8 a[2][2], b[4][2];
      #pragma unroll
      for (int i = 0; i < 2; i++)
        #pragma unroll
        for (int h = 0; h < 2; h++)
          a[i][h] = *(const half8*)(Bc + (wq * 2 + i) * 1024 + h * 512 + lane * 8);
      #pragma unroll
      for (int j = 0; j < 4; j++)
        #pragma unroll
        for (int h = 0; h < 2; h++)
          b[j][h] = *(const half8*)(Bc + 4096 + (wc * 4 + j) * 1024 + h * 512 + lane * 8);
      #pragma unroll
      for (int h = 0; h < 2; h++)
        #pragma unroll
        for (int i = 0; i < 2; i++)
          #pragma unroll
          for (int j = 0; j < 4; j++)
            acc[i][j] = __builtin_amdgcn_mfma_f32_16x16x32_f16(a[i][h], b[j][h], acc[i][j], 0, 0, 0);
      __syncthreads();
    }

    // epilogue: f16 transposed scores into buf1 region (buf1 fully consumed)
    #pragma unroll
    for (int j = 0; j < 4; j++) {
      int cl = wc * 64 + j * 16 + col16;
      float ncv = nC[c0 + cl];
      #pragma unroll
      for (int i = 0; i < 2; i++) {
        half4v st;
        st.x = (_Float16)(ncv - 2.f * acc[i][j][0]);
        st.y = (_Float16)(ncv - 2.f * acc[i][j][1]);
        st.z = (_Float16)(ncv - 2.f * acc[i][j][2]);
        st.w = (_Float16)(ncv - 2.f * acc[i][j][3]);
        *(half4v*)&Sh[(size_t)cl * 68 + wq * 32 + i * 16 + quad * 4] = st;
      }
    }
    __syncthreads();

    // scan: 4 threads/row, 32 cands each; row-contiguous u16 -> conflict-free
    for (int c = h_scan * 32; c < h_scan * 32 + 32; c++) {
      float s = (float)Sh[c * 68 + r_scan];
      u64 key = ((u64)sortable(s) << 32) | (unsigned)(c0 + c);
      if (key < keys[M - 1]) {
        keys[M - 1] = key;
        #pragma unroll
        for (int p = M - 1; p > 0; p--) {
          if (keys[p] < keys[p - 1]) { u64 tmp = keys[p]; keys[p] = keys[p - 1]; keys[p - 1] = tmp; }
        }
      }
    }
    __syncthreads();   // scan done before next tile's K-loop overwrites buf1
  }

  // merge 4 partial lists per row -> sorted top-M for this split
  #pragma unroll
  for (int q = 0; q < M; q++)
    Lb[((size_t)h_scan * 64 + r_scan) * M + q] = keys[q];
  __syncthreads();
  if (tid < 64) {
    int p0 = 0, p1 = 0, p2 = 0, p3 = 0;
    const u64* L0 = Lb + (size_t)(0 * 64 + tid) * M;
    const u64* L1 = Lb + (size_t)(1 * 64 + tid) * M;
    const u64* L2 = Lb + (size_t)(2 * 64 + tid) * M;
    const u64* L3 = Lb + (size_t)(3 * 64 + tid) * M;
    size_t off = (size_t)(row0 + tid) * ((size_t)NSPL * M) + (size_t)split * M;
    #pragma unroll
    for (int q = 0; q < M; q++) {
      u64 k0 = (p0 < M) ? L0[p0] : ~0ULL;
      u64 k1 = (p1 < M) ? L1[p1] : ~0ULL;
      u64 k2 = (p2 < M) ? L2[p2] : ~0ULL;
      u64 k3 = (p3 < M) ? L3[p3] : ~0ULL;
      u64 b01 = k0 < k1 ? k0 : k1;
      u64 b23 = k2 < k3 ? k2 : k3;
      u64 b = b01 < b23 ? b01 : b23;
      if (b == k0) p0++; else if (b == k1) p1++; else if (b == k2) p2++; else p3++;
      outS[off + q] = unsortable((unsigned)(b >> 32));
      outI[off + q] = (int)(unsigned)b;
    }
  }
}

// R5 grid: blocks [0,512) knn-reg (16 c-tiles, M=8, 4 splits) — long, first;
// [512,1024) mixup (4 c-tiles, M=16, 8 splits). 3 blocks/CU.
__global__ __launch_bounds__(256, 3) void k_knn_all(const _Float16* __restrict__ Xh,
                                                    const float* __restrict__ n_all,
                                                    float* __restrict__ tk1s, int* __restrict__ tk1i,
                                                    float* __restrict__ tk2s, int* __restrict__ tk2i) {
  __shared__ __align__(16) char smem[49152];
  int bx = blockIdx.x;
  if (bx < 512) {            // knn regularizer: 8192 q vs 8192 c, 4 splits, top-8
    int qblk = bx & 127, split = bx >> 7;
    knn_body<8, 4>(Xh + (size_t)(qblk * 64) * D, Xh, n_all,
                   split * 2048, 16, qblk * 64, split, tk2s, tk2i, smem);
  } else {                   // mixup: 4096 mixed q vs 4096 x c, 8 splits, top-16
    int b = bx - 512;
    int qblk = b & 63, split = b >> 6;
    knn_body<16, 8>(Xh + (size_t)(N0 + qblk * 64) * D, Xh, n_all,
                    split * 512, 4, qblk * 64, split, tk1s, tk1i, smem);
  }
}

// exact fp32 re-rank mixup: rank-select top-16 of 128 -> exact -> mode(11)
__global__ __launch_bounds__(256) void k_rr1(const float* __restrict__ x, const int* __restrict__ perm,
                                             const float* __restrict__ lam_p,
                                             const float* __restrict__ tks, const int* __restrict__ tki,
                                             const float* __restrict__ n_all, const float* __restrict__ y,
                                             float* __restrict__ y_all) {
  __shared__ u64 kl[128];
  __shared__ int sidx[16];
  __shared__ float sdot[16];
  int i = blockIdx.x;
  int t = threadIdx.x;
  float lam = lam_p[0], om = 1.f - lam;
  if (t < 128) {
    float s = tks[(size_t)i * 128 + t];
    int id = tki[(size_t)i * 128 + t];
    kl[t] = ((u64)sortable(s) << 32) | (unsigned)id;
  }
  __syncthreads();
  if (t < 128) {
    u64 me = kl[t];
    int rank = 0;
    for (int j = 0; j < 128; j++) rank += (kl[j] < me) ? 1 : 0;
    if (rank < 16) sidx[rank] = (int)(unsigned)me;
  }
  __syncthreads();
  int g = t >> 4, l16 = t & 15;
  int c = sidx[g];
  float dot = 0.f;
  for (int d0 = l16 * 4; d0 < D; d0 += 64) {
    float4 q4 = ld_row4(x, perm, lam, om, N0 + i, d0);
    float4 c4 = *(const float4*)(x + (size_t)c * D + d0);
    dot += q4.x*c4.x + q4.y*c4.y + q4.z*c4.z + q4.w*c4.w;
  }
  #pragma unroll
  for (int o = 8; o > 0; o >>= 1) dot += __shfl_down(dot, o, 16);
  if (l16 == 0) sdot[g] = n_all[c] - 2.f * dot;
  __syncthreads();
  if (t == 0) {
    float es[16]; int ei[16];
    for (int q = 0; q < 16; q++) { es[q] = sdot[q]; ei[q] = sidx[q]; }
    for (int a = 1; a < 16; a++) {
      float s = es[a]; int id = ei[a];
      int b = a - 1;
      while (b >= 0 && (es[b] > s || (es[b] == s && ei[b] > id))) {
        es[b + 1] = es[b]; ei[b + 1] = ei[b]; b--;
      }
      es[b + 1] = s; ei[b + 1] = id;
    }
    float lab[KMIX];
    for (int q = 0; q < KMIX; q++) lab[q] = y[ei[q]];
    float best = 3.0e38f; int bestc = 0;
    for (int q = 0; q < KMIX; q++) {
      int cnt = 0;
      for (int r = 0; r < KMIX; r++) cnt += (lab[r] == lab[q]) ? 1 : 0;
      if (cnt > bestc || (cnt == bestc && lab[q] < best)) { bestc = cnt; best = lab[q]; }
    }
    y_all[N0 + i] = best;
  }
}

// exact fp32 re-rank knn reg: rank-select top-8 of 32 -> exact -> drop self, mode(3)
__global__ __launch_bounds__(256) void k_rr2(const float* __restrict__ x, const int* __restrict__ perm,
                                             const float* __restrict__ lam_p,
                                             const float* __restrict__ tks, const int* __restrict__ tki,
                                             const float* __restrict__ n_all, const float* __restrict__ y_all,
                                             float* __restrict__ ksq) {
  __shared__ u64 kl[32];
  __shared__ int sidx[8];
  __shared__ float sdot[8];
  int i = blockIdx.x;
  int t = threadIdx.x;
  float lam = lam_p[0], om = 1.f - lam;
  if (t < 32) {
    float s = tks[(size_t)i * 32 + t];
    int id = tki[(size_t)i * 32 + t];
    kl[t] = ((u64)sortable(s) << 32) | (unsigned)id;
  }
  __syncthreads();
  if (t < 32) {
    u64 me = kl[t];
    int rank = 0;
    #pragma unroll
    for (int j = 0; j < 32; j++) rank += (kl[j] < me) ? 1 : 0;
    if (rank < 8) sidx[rank] = (int)(unsigned)me;
  }
  __syncthreads();
  int g = t >> 5, l32 = t & 31;
  int c = sidx[g];
  float dot = 0.f;
  for (int d0 = l32 * 4; d0 < D; d0 += 128) {
    float4 q4 = ld_row4(x, perm, lam, om, i, d0);
    float4 c4 = ld_row4(x, perm, lam, om, c, d0);
    dot += q4.x*c4.x + q4.y*c4.y + q4.z*c4.z + q4.w*c4.w;
  }
  #pragma unroll
  for (int o = 16; o > 0; o >>= 1) dot += __shfl_down(dot, o, 32);
  if (l32 == 0) sdot[g] = n_all[c] - 2.f * dot;
  __syncthreads();
  if (t == 0) {
    float es[8]; int ei[8];
    for (int q = 0; q < 8; q++) { es[q] = sdot[q]; ei[q] = sidx[q]; }
    for (int a = 1; a < 8; a++) {
      float s = es[a]; int id = ei[a];
      int b = a - 1;
      while (b >= 0 && (es[b] > s || (es[b] == s && ei[b] > id))) {
        es[b + 1] = es[b]; ei[b + 1] = ei[b]; b--;
      }
      es[b + 1] = s; ei[b + 1] = id;
    }
    float l1 = y_all[ei[1]], l2 = y_all[ei[2]], l3 = y_all[ei[3]];
    int c1 = 1 + (int)(l2 == l1) + (int)(l3 == l1);
    int c2 = 1 + (int)(l1 == l2) + (int)(l3 == l2);
    int c3 = 1 + (int)(l1 == l3) + (int)(l2 == l3);
    int mc = c1 > c2 ? c1 : c2; mc = mc > c3 ? mc : c3;
    float mv = 3.0e38f;
    if (c1 == mc) mv = fminf(mv, l1);
    if (c2 == mc) mv = fminf(mv, l2);
    if (c3 == mc) mv = fminf(mv, l3);
    float d = mv - y_all[i];
    ksq[i] = d * d;
  }
}

// per-class mean via LDS row-list; f16 muH [128][512], nmu_pad, counts.
__global__ __launch_bounds__(256) void k_stats2h(const float* __restrict__ x, const int* __restrict__ perm,
                                                 const float* __restrict__ lam_p, const float* __restrict__ y_all,
                                                 _Float16* __restrict__ muH, float* __restrict__ nmu_pad,
                                                 float* __restrict__ counts) {
  __shared__ int cnt;
  __shared__ int lst[NUM];
  __shared__ int lstp[NUM];
  __shared__ float red[256];
  int c = blockIdx.x;
  int t = threadIdx.x;
  if (c >= NCLS) {
    for (int d = t; d < D; d += 256) muH[(size_t)c * D + d] = (_Float16)0.f;
    if (t == 0) { nmu_pad[c] = 0.f; counts[c] = 0.f; }
    return;
  }
  float lam = lam_p[0], om = 1.f - lam;
  float fc = (float)c;
  if (t == 0) cnt = 0;
  __syncthreads();
  for (int i = t; i < NUM; i += 256) {
    if (y_all[i] == fc) {
      int pos = atomicAdd(&cnt, 1);
      lst[pos] = i;
      lstp[pos] = (i >= N0) ? perm[i - N0] : 0;
    }
  }
  __syncthreads();
  int n = cnt;
  float a0 = 0.f, a1 = 0.f;
  for (int m = 0; m < n; m++) {
    int i = lst[m];
    if (i < N0) {
      a0 += x[(size_t)i * D + t];
      a1 += x[(size_t)i * D + t + 256];
    } else {
      int rr = i - N0, p = lstp[m];
      a0 += lam * x[(size_t)rr * D + t] + om * x[(size_t)p * D + t];
      a1 += lam * x[(size_t)rr * D + t + 256] + om * x[(size_t)p * D + t + 256];
    }
  }
  float inv = 1.f / fmaxf((float)n, 1.f);
  float v0 = a0 * inv, v1 = a1 * inv;
  muH[(size_t)c * D + t] = (_Float16)v0;
  muH[(size_t)c * D + t + 256] = (_Float16)v1;
  red[t] = v0 * v0 + v1 * v1;
  __syncthreads();
  for (int o = 128; o > 0; o >>= 1) { if (t < o) red[t] += red[t + o]; __syncthreads(); }
  if (t == 0) { nmu_pad[c] = red[0]; counts[c] = (float)n; }
}

// GM loss via MFMA GEMM (64 rows x 128 padded classes per block), R5/R6-verified
__global__ __launch_bounds__(256) void k_gm2(const _Float16* __restrict__ Xh,
                                             const _Float16* __restrict__ muH,
                                             const float* __restrict__ nmu_pad,
                                             const float* __restrict__ counts,
                                             const float* __restrict__ n_all,
                                             const float* __restrict__ y_all,
                                             float* __restrict__ rloss) {
  __shared__ __align__(16) char smem[49152];
  float* Ss = (float*)smem;
  _Float16* St = (_Float16*)smem;

  int tid = threadIdx.x;
  int wave = tid >> 6, lane = tid & 63;
  int wq = wave >> 1, wc = wave & 1;
  int col16 = lane & 15, quad = lane >> 4;
  int qb = blockIdx.x * 64;

  const _Float16* qg = Xh + (size_t)(qb + wave * 16 + col16) * D + quad * 8;
  int csegA = 2 * wave, csegB = 2 * wave + 1;
  const _Float16* cgA = muH + (size_t)(csegA * 16 + col16) * D + quad * 8;
  const _Float16* cgB = cgA + (size_t)16 * D;
  int ldsQ = wave * 1024 + lane * 8;
  int ldsCA = 4096 + csegA * 1024 + lane * 8;
  int ldsCB = 4096 + csegB * 1024 + lane * 8;

  f32x4 acc[2][4];
  #pragma unroll
  for (int i = 0; i < 2; i++)
    #pragma unroll
    for (int j = 0; j < 4; j++) acc[i][j] = (f32x4){0.f, 0.f, 0.f, 0.f};

  gld_lds16(qg,       St + ldsQ);
  gld_lds16(qg + 32,  St + ldsQ + 512);
  gld_lds16(cgA,      St + ldsCA);
  gld_lds16(cgA + 32, St + ldsCA + 512);
  gld_lds16(cgB,      St + ldsCB);
  gld_lds16(cgB + 32, St + ldsCB + 512);
  __syncthreads();

  #pragma unroll
  for (int t = 0; t < 8; t++) {
    const int cur = t & 1;
    if (t < 7) {
      int kk = (t + 1) * 64;
      _Float16* B = St + (cur ^ 1) * 12288;
      gld_lds16(qg + kk,       B + ldsQ);
      gld_lds16(qg + kk + 32,  B + ldsQ + 512);
      gld_lds16(cgA + kk,      B + ldsCA);
      gld_lds16(cgA + kk + 32, B + ldsCA + 512);
      gld_lds16(cgB + kk,      B + ldsCB);
      gld_lds16(cgB + kk + 32, B + ldsCB + 512);
    }
    const _Float16* Bc = St + cur * 12288;
    half8 a[2][2], b[4][2];
    #pragma unroll
    for (int i = 0; i < 2; i++)
      #pragma unroll
      for (int h = 0; h < 2; h++)
        a[i][h] = *(const half8*)(Bc + (wq * 2 + i) * 1024 + h * 512 + lane * 8);
    #pragma unroll
    for (int j = 0; j < 4; j++)
      #pragma unroll
      for (int h = 0; h < 2; h++)
        b[j][h] = *(const half8*)(Bc + 4096 + (wc * 4 + j) * 1024 + h * 512 + lane * 8);
    #pragma unroll
    for (int h = 0; h < 2; h++)
      #pragma unroll
      for (int i = 0; i < 2; i++)
        #pragma unroll
        for (int j = 0; j < 4; j++)
          acc[i][j] = __builtin_amdgcn_mfma_f32_16x16x32_f16(a[i][h], b[j][h], acc[i][j], 0, 0, 0);
    __syncthreads();
  }

  #pragma unroll
  for (int j = 0; j < 4; j++) {
    int c_local = wc * 64 + j * 16 + col16;
    float ncv = nmu_pad[c_local];
    #pragma unroll
    for (int i = 0; i < 2; i++) {
      float4 st;
      st.x = ncv - 2.f * acc[i][j][0];
      st.y = ncv - 2.f * acc[i][j][1];
      st.z = ncv - 2.f * acc[i][j][2];
      st.w = ncv - 2.f * acc[i][j][3];
      *(float4*)&Ss[(size_t)c_local * 68 + wq * 32 + i * 16 + quad * 4] = st;
    }
  }
  __syncthreads();

  int r = tid & 63, h = tid >> 6;
  float* redm = (float*)(smem + 35840);
  float* mrow = (float*)(smem + 36864);
  float* Sp   = (float*)(smem + 37120);
  float* Ep   = (float*)(smem + 38144);
  float* Yp   = (float*)(smem + 39168);

  float mymin = 3.0e38f;
  for (int c = h * 32; c < h * 32 + 32; c++) {
    if (c < NCLS && counts[c] > 0.f) mymin = fminf(mymin, Ss[c * 68 + r]);
  }
  redm[h * 64 + r] = mymin;
  __syncthreads();
  if (tid < 64) {
    float ms = fminf(fminf(redm[tid], redm[64 + tid]), fminf(redm[128 + tid], redm[192 + tid]));
    mrow[tid] = ms;
  }
  __syncthreads();
  float ms = mrow[r];
  int yc = (int)y_all[qb + r];
  float Sv = 0.f, Se2 = 0.f, ey = 0.f;
  for (int c = h * 32; c < h * 32 + 32; c++) {
    if (c < NCLS && counts[c] > 0.f) {
      float e = expf(-0.5f * (Ss[c * 68 + r] - ms));
      Sv += e; Se2 += e * e;
      if (c == yc) ey = e;
    }
  }
  Sp[h * 64 + r] = Sv; Ep[h * 64 + r] = Se2; Yp[h * 64 + r] = ey;
  __syncthreads();
  if (tid < 64) {
    float S4 = Sp[tid] + Sp[64 + tid] + Sp[128 + tid] + Sp[192 + tid];
    float E4 = Ep[tid] + Ep[64 + tid] + Ep[128 + tid] + Ep[192 + tid];
    float Y4 = Yp[tid] + Yp[64 + tid] + Yp[128 + tid] + Yp[192 + tid];
    float m = n_all[qb + tid] + mrow[tid];
    float E = expf(-0.5f * m);          // underflows to 0 -> pi == 0 -> loss 1
    float denom = E * S4 + 1e-15f;
    float f = E / denom;
    rloss[qb + tid] = E4 * f * f - 2.f * Y4 * f + 1.f;
  }
}

__global__ __launch_bounds__(256) void k_final_fast(const float* __restrict__ row_loss,
                                                    const float* __restrict__ ksq, float* __restrict__ out) {
  __shared__ float red[256];
  int t = threadIdx.x;
  float s = 0.f;
  for (int i = t; i < NUM; i += 256) s += row_loss[i] + 0.01f * ksq[i];
  red[t] = s;
  __syncthreads();
  for (int o = 128; o > 0; o >>= 1) { if (t < o) red[t] += red[t + o]; __syncthreads(); }
  if (t == 0) out[0] = red[0] / (float)NUM;
}

// ================= fp32 fallback path (R2, passed absmax 0.0) =================
#define QT 32
#define CTF 128
#define BKF 32

__global__ __launch_bounds__(64) void k_norms(const float* __restrict__ x, const int* __restrict__ perm,
                                              const float* __restrict__ lam_p, float* __restrict__ n_all) {
  int i = blockIdx.x;
  float lam = lam_p[0], om = 1.0f - lam;
  int t = threadIdx.x;
  float4 a = ld_row4(x, perm, lam, om, i, t * 4);
  float4 b = ld_row4(x, perm, lam, om, i, t * 4 + 256);
  float s = a.x*a.x + a.y*a.y + a.z*a.z + a.w*a.w
          + b.x*b.x + b.y*b.y + b.z*b.z + b.w*b.w;
  #pragma unroll
  for (int o = 32; o > 0; o >>= 1) s += __shfl_down(s, o, 64);
  if (t == 0) n_all[i] = s;
}

template<int KK>
__global__ __launch_bounds__(256) void k_knn_f32(const float* __restrict__ x, const int* __restrict__ perm,
                                                 const float* __restrict__ lam_p, int qstart,
                                                 const float* __restrict__ nC, int candPerSplit, int nsplits,
                                                 float* __restrict__ outS, int* __restrict__ outI) {
  __shared__ float Qs[BKF][QT + 4];
  __shared__ float Cs[BKF][CTF + 4];
  __shared__ float Sf[QT][CTF + 4];

  int tid = threadIdx.x;
  float lam = lam_p[0], om = 1.0f - lam;
  int qbase = blockIdx.x * QT;
  int cb = blockIdx.y * candPerSplit;
  int ce = cb + candPerSplit;

  int cx = tid & 31;
  int ry = tid >> 5;
  int lr = tid >> 3;
  int kc = (tid & 7) * 4;

  float ks[KK]; int ki[KK];
  #pragma unroll
  for (int q = 0; q < KK; q++) { ks[q] = 3.0e38f; ki[q] = 0x7fffffff; }

  for (int c0 = cb; c0 < ce; c0 += CTF) {
    float acc[4][4];
    #pragma unroll
    for (int i = 0; i < 4; i++)
      #pragma unroll
      for (int j = 0; j < 4; j++) acc[i][j] = 0.f;

    for (int kk = 0; kk < D; kk += BKF) {
      __syncthreads();
      {
        float4 v = ld_row4(x, perm, lam, om, qstart + qbase + lr, kk + kc);
        Qs[kc + 0][lr] = v.x; Qs[kc + 1][lr] = v.y; Qs[kc + 2][lr] = v.z; Qs[kc + 3][lr] = v.w;
      }
      #pragma unroll
      for (int rr = 0; rr < 4; rr++) {
        int r = lr + rr * 32;
        float4 v = ld_row4(x, perm, lam, om, c0 + r, kk + kc);
        Cs[kc + 0][r] = v.x; Cs[kc + 1][r] = v.y; Cs[kc + 2][r] = v.z; Cs[kc + 3][r] = v.w;
      }
      __syncthreads();
      #pragma unroll
      for (int k = 0; k < BKF; k++) {
        float4 a4 = *(const float4*)&Qs[k][ry * 4];
        float4 b4 = *(const float4*)&Cs[k][cx * 4];
        float av[4] = {a4.x, a4.y, a4.z, a4.w};
        float bv[4] = {b4.x, b4.y, b4.z, b4.w};
        #pragma unroll
        for (int i = 0; i < 4; i++)
          #pragma unroll
          for (int j = 0; j < 4; j++) acc[i][j] += av[i] * bv[j];
      }
    }
    __syncthreads();
    {
      float4 nc4 = *(const float4*)&nC[c0 + cx * 4];
      float ncv[4] = {nc4.x, nc4.y, nc4.z, nc4.w};
      #pragma unroll
      for (int i = 0; i < 4; i++)
        #pragma unroll
        for (int j = 0; j < 4; j++)
          Sf[ry * 4 + i][cx * 4 + j] = ncv[j] - 2.0f * acc[i][j];
    }
    __syncthreads();
    if (tid < QT) {
      for (int c = 0; c < CTF; c++) {
        float s = Sf[tid][c];
        int j = c0 + c;
        bool worse = (s > ks[KK - 1]) || (s == ks[KK - 1] && j > ki[KK - 1]);
        if (!worse) {
          ks[KK - 1] = s; ki[KK - 1] = j;
          #pragma unroll
          for (int p = KK - 1; p > 0; p--) {
            bool sw = (ks[p] < ks[p - 1]) || (ks[p] == ks[p - 1] && ki[p] < ki[p - 1]);
            if (sw) {
              float ts = ks[p]; ks[p] = ks[p - 1]; ks[p - 1] = ts;
              int ti = ki[p]; ki[p] = ki[p - 1]; ki[p - 1] = ti;
            }
          }
        }
      }
    }
  }

  if (tid < QT) {
    int row = qbase + tid;
    size_t off = (size_t)row * (nsplits * KK) + (size_t)blockIdx.y * KK;
    #pragma unroll
    for (int q = 0; q < KK; q++) { outS[off + q] = ks[q]; outI[off + q] = ki[q]; }
  }
}

__global__ __launch_bounds__(256) void k_final1(const float* __restrict__ tks, const int* __restrict__ tki,
                                                const float* __restrict__ y, float* __restrict__ y_all) {
  int i = blockIdx.x * 256 + threadIdx.x;
  if (i >= N0) return;
  const float* sb = tks + (size_t)i * 44;
  const int* ib = tki + (size_t)i * 44;
  int p0 = 0, p1 = 0, p2 = 0, p3 = 0;
  float lab[KMIX];
  #pragma unroll
  for (int q = 0; q < KMIX; q++) {
    float bs = 3.0e38f; int bi = 0x7fffffff; int w = 0;
    if (p0 < 11) { float s = sb[p0];      int id = ib[p0];      if (s < bs || (s == bs && id < bi)) { bs = s; bi = id; w = 0; } }
    if (p1 < 11) { float s = sb[11 + p1]; int id = ib[11 + p1]; if (s < bs || (s == bs && id < bi)) { bs = s; bi = id; w = 1; } }
    if (p2 < 11) { float s = sb[22 + p2]; int id = ib[22 + p2]; if (s < bs || (s == bs && id < bi)) { bs = s; bi = id; w = 2; } }
    if (p3 < 11) { float s = sb[33 + p3]; int id = ib[33 + p3]; if (s < bs || (s == bs && id < bi)) { bs = s; bi = id; w = 3; } }
    if (w == 0) p0++; else if (w == 1) p1++; else if (w == 2) p2++; else p3++;
    lab[q] = y[bi];
  }
  float best = 3.0e38f; int bestc = 0;
  #pragma unroll
  for (int q = 0; q < KMIX; q++) {
    int c = 0;
    #pragma unroll
    for (int r = 0; r < KMIX; r++) c += (lab[r] == lab[q]) ? 1 : 0;
    if (c > bestc || (c == bestc && lab[q] < best)) { bestc = c; best = lab[q]; }
  }
  y_all[N0 + i] = best;
}

__global__ __launch_bounds__(128) void k_stats(const float* __restrict__ x, const int* __restrict__ perm,
                                               const float* __restrict__ lam_p, const float* __restrict__ y_all,
                                               float* __restrict__ mu_sum, float* __restrict__ counts) {
  int i = blockIdx.x;
  float lam = lam_p[0], om = 1.0f - lam;
  int c = (int)y_all[i];
  float* ms = mu_sum + (size_t)c * D;
  int t = threadIdx.x;
  float4 v = ld_row4(x, perm, lam, om, i, t * 4);
  atomicAdd(&ms[t * 4 + 0], v.x);
  atomicAdd(&ms[t * 4 + 1], v.y);
  atomicAdd(&ms[t * 4 + 2], v.z);
  atomicAdd(&ms[t * 4 + 3], v.w);
  if (t == 0) atomicAdd(&counts[c], 1.0f);
}

__global__ __launch_bounds__(256) void k_mufin(const float* __restrict__ mu_sum, const float* __restrict__ counts,
                                               float* __restrict__ muT, float* __restrict__ nmu) {
  __shared__ float red[256];
  int c = blockIdx.x;
  float inv = 1.0f / fmaxf(counts[c], 1.0f);
  int t = threadIdx.x;
  float v0 = mu_sum[(size_t)c * D + t] * inv;
  float v1 = mu_sum[(size_t)c * D + t + 256] * inv;
  muT[(size_t)t * NCLS + c] = v0;
  muT[(size_t)(t + 256) * NCLS + c] = v1;
  red[t] = v0 * v0 + v1 * v1;
  __syncthreads();
  for (int o = 128; o > 0; o >>= 1) { if (t < o) red[t] += red[t + o]; __syncthreads(); }
  if (t == 0) nmu[c] = red[0];
}

__global__ __launch_bounds__(256) void k_final2(const float* __restrict__ t2s, const int* __restrict__ t2i,
                                                const float* __restrict__ y_all, float* __restrict__ knn_acc) {
  __shared__ float red[256];
  int i = blockIdx.x * 256 + threadIdx.x;
  float dd2 = 0.f;
  if (i < NUM) {
    const float* sA = t2s + (size_t)i * 8; const float* sB = sA + 4;
    const int* iA = t2i + (size_t)i * 8;   const int* iB = iA + 4;
    int pa = 0, pb = 0;
    int midx[4];
    #pragma unroll
    for (int q = 0; q < 4; q++) {
      float sa = (pa < 4) ? sA[pa] : 3.0e38f;
      float sb = (pb < 4) ? sB[pb] : 3.0e38f;
      int ia = (pa < 4) ? iA[pa] : 0x7fffffff;
      int ib = (pb < 4) ? iB[pb] : 0x7fffffff;
      bool ta = (sa < sb) || (sa == sb && ia < ib);
      midx[q] = ta ? ia : ib;
      if (ta) pa++; else pb++;
    }
    float l1 = y_all[midx[1]], l2 = y_all[midx[2]], l3 = y_all[midx[3]];
    int c1 = 1 + (int)(l2 == l1) + (int)(l3 == l1);
    int c2 = 1 + (int)(l1 == l2) + (int)(l3 == l2);
    int c3 = 1 + (int)(l1 == l3) + (int)(l2 == l3);
    int mc = c1 > c2 ? c1 : c2; mc = mc > c3 ? mc : c3;
    float mv = 3.0e38f;
    if (c1 == mc) mv = fminf(mv, l1);
    if (c2 == mc) mv = fminf(mv, l2);
    if (c3 == mc) mv = fminf(mv, l3);
    float d = mv - y_all[i];
    dd2 = d * d;
  }
  red[threadIdx.x] = dd2;
  __syncthreads();
  for (int o = 128; o > 0; o >>= 1) { if (threadIdx.x < o) red[threadIdx.x] += red[threadIdx.x + o]; __syncthreads(); }
  if (threadIdx.x == 0) atomicAdd(knn_acc, red[0]);
}

__global__ __launch_bounds__(128) void k_gm(const float* __restrict__ x, const int* __restrict__ perm,
                                            const float* __restrict__ lam_p, const float* __restrict__ y_all,
                                            const float* __restrict__ n_all, const float* __restrict__ muT,
                                            const float* __restrict__ nmu, const float* __restrict__ counts,
                                            float* __restrict__ row_loss) {
  __shared__ float red[128];
  int i = blockIdx.x;
  int t = threadIdx.x;
  float lam = lam_p[0], om = 1.0f - lam;
  bool valid = (t < NCLS) && (counts[t] > 0.f);
  float d2 = 3.0e38f;
  if (t < NCLS) {
    float dot = 0.f;
    for (int d = 0; d < D; d += 4) {
      float4 v = ld_row4(x, perm, lam, om, i, d);
      dot += v.x * muT[(size_t)(d + 0) * NCLS + t];
      dot += v.y * muT[(size_t)(d + 1) * NCLS + t];
      dot += v.z * muT[(size_t)(d + 2) * NCLS + t];
      dot += v.w * muT[(size_t)(d + 3) * NCLS + t];
    }
    d2 = n_all[i] + nmu[t] - 2.f * dot;
  }
  red[t] = valid ? d2 : 3.0e38f;
  __syncthreads();
  for (int o = 64; o > 0; o >>= 1) { if (t < o) red[t] = fminf(red[t], red[t + o]); __syncthreads(); }
  float m = red[0];
  __syncthreads();
  float e = valid ? expf(-0.5f * (d2 - m)) : 0.f;
  red[t] = e;
  __syncthreads();
  for (int o = 64; o > 0; o >>= 1) { if (t < o) red[t] += red[t + o]; __syncthreads(); }
  float S = red[0];
  __syncthreads();
  float E = expf(-0.5f * m);
  float denom = E * S + 1e-15f;
  float pi = e * E / denom;
  pi = fminf(fmaxf(pi, 0.f), 1.f);
  int yc = (int)y_all[i];
  float term = pi * pi - 2.f * ((t == yc) ? pi : 0.f);
  red[t] = valid ? term : 0.f;
  __syncthreads();
  for (int o = 64; o > 0; o >>= 1) { if (t < o) red[t] += red[t + o]; __syncthreads(); }
  if (t == 0) row_loss[i] = red[0] + 1.0f;
}

__global__ __launch_bounds__(256) void k_final_slow(const float* __restrict__ row_loss,
                                                    const float* __restrict__ knn_acc, float* __restrict__ out) {
  __shared__ float red[256];
  int t = threadIdx.x;
  float s = 0.f;
  for (int i = t; i < NUM; i += 256) s += row_loss[i];
  red[t] = s;
  __syncthreads();
  for (int o = 128; o > 0; o >>= 1) { if (t < o) red[t] += red[t + o]; __syncthreads(); }
  if (t == 0) out[0] = red[0] / (float)NUM + 0.01f * (knn_acc[0] / (float)NUM);
}

extern "C" void kernel_launch(void* const* d_in, const int* in_sizes, int n_in,
                              void* d_out, int out_size, void* d_ws, size_t ws_size,
                              hipStream_t stream) {
  const float* x   = (const float*)d_in[0];
  const float* y   = (const float*)d_in[1];
  const float* lam = (const float*)d_in[2];
  const int* perm  = (const int*)d_in[3];
  float* ws = (float*)d_ws;

  float* n_all  = ws + OFF_NALL;
  float* y_all  = ws + OFF_YALL;
  float* rloss  = ws + OFF_RLOSS;
  float* ksq    = ws + OFF_KSQ;
  float* mu_sum = ws + OFF_MUSUM;
  float* counts = ws + OFF_CNT;
  float* knn_acc= ws + OFF_KNN;
  float* nmu    = ws + OFF_NMU;
  float* muT    = ws + OFF_MUT;
  float* tk1s   = ws + OFF_TK1S;
  int*   tk1i   = (int*)(ws + OFF_TK1I);
  float* tk2s   = ws + OFF_TK2S;
  int*   tk2i   = (int*)(ws + OFF_TK2I);
  _Float16* Xh  = (_Float16*)(ws + OFF_XH);
  _Float16* muH = (_Float16*)(ws + OFF_MUSUM);
  float* nmu_pad= ws + OFF_MUT;

  bool fast = ws_size >= NEED_BYTES;   // constant per-process: same path every call

  if (fast) {
    k_prep<<<NUM, 64, 0, stream>>>(x, y, perm, lam, Xh, n_all, y_all);
    k_knn_all<<<1024, 256, 0, stream>>>(Xh, n_all, tk1s, tk1i, tk2s, tk2i);
    k_rr1<<<N0, 256, 0, stream>>>(x, perm, lam, tk1s, tk1i, n_all, y, y_all);
    k_stats2h<<<128, 256, 0, stream>>>(x, perm, lam, y_all, muH, nmu_pad, counts);
    k_rr2<<<NUM, 256, 0, stream>>>(x, perm, lam, tk2s, tk2i, n_all, y_all, ksq);
    k_gm2<<<NUM / 64, 256, 0, stream>>>(Xh, muH, nmu_pad, counts, n_all, y_all, rloss);
    k_final_fast<<<1, 256, 0, stream>>>(rloss, ksq, (float*)d_out);
  } else {
    k_y<<<(N0 + 255) / 256, 256, 0, stream>>>(y, y_all);
    k_zero<<<(ZERO_N + 255) / 256, 256, 0, stream>>>(mu_sum, ZERO_N);
    k_norms<<<NUM, 64, 0, stream>>>(x, perm, lam, n_all);
    dim3 g1(N0 / QT, 4);
    k_knn_f32<KMIX><<<g1, 256, 0, stream>>>(x, perm, lam, N0, n_all, N0 / 4, 4, tk1s, tk1i);
    k_final1<<<(N0 + 255) / 256, 256, 0, stream>>>(tk1s, tk1i, y, y_all);
    k_stats<<<NUM, 128, 0, stream>>>(x, perm, lam, y_all, mu_sum, counts);
    k_mufin<<<NCLS, 256, 0, stream>>>(mu_sum, counts, muT, nmu);
    dim3 g2(NUM / QT, 2);
    k_knn_f32<4><<<g2, 256, 0, stream>>>(x, perm, lam, 0, n_all, NUM / 2, 2, tk2s, tk2i);
    k_final2<<<NUM / 256, 256, 0, stream>>>(tk2s, tk2i, y_all, knn_acc);
    k_gm<<<NUM, 128, 0, stream>>>(x, perm, lam, y_all, n_all, muT, nmu, counts, rloss);
    k_final_slow<<<1, 256, 0, stream>>>(rloss, knn_acc, (float*)d_out);
  }
}